// Round 23
// baseline (142.989 us; speedup 1.0000x reference)
//
#include <hip/hip_runtime.h>
#include <hip/hip_bf16.h>

typedef __attribute__((ext_vector_type(4))) float f32x4;
typedef __attribute__((ext_vector_type(16))) float f32x16;
typedef __attribute__((ext_vector_type(8))) __bf16 bf16x8;
typedef unsigned short u16;
typedef unsigned int u32;
typedef __attribute__((ext_vector_type(4))) u16 u16x4;

#define OPHALF 4194304  /* 8*4096*128 elems per part */

// ---------- helpers ----------
__device__ __forceinline__ u16 f2bf(float f) {
    u32 u = __builtin_bit_cast(u32, f);
    u32 r = (u + 0x7FFFu + ((u >> 16) & 1u)) >> 16;
    return (u16)r;
}
__device__ __forceinline__ float bf2f(u16 h) {
    return __builtin_bit_cast(float, ((u32)h) << 16);
}
__device__ __forceinline__ bf16x8 ld_frag(const u16* p) {
    uint4 v = *reinterpret_cast<const uint4*>(p);
    return __builtin_bit_cast(bf16x8, v);
}
__device__ __forceinline__ void gld_lds(const u16* gp, u16* lp) {
    __builtin_amdgcn_global_load_lds(
        (const __attribute__((address_space(1))) u32*)gp,
        (__attribute__((address_space(3))) u32*)lp, 16, 0, 0);
}
__device__ __forceinline__ u32 pk_bf16(float lo, float hi) {
    u32 r;
    asm("v_cvt_pk_bf16_f32 %0, %1, %2" : "=v"(r) : "v"(lo), "v"(hi));
    return r;
}
__device__ __forceinline__ void unp8(uint4 v, float* f) {
    f[0] = bf2f((u16)(v.x & 0xffffu)); f[1] = bf2f((u16)(v.x >> 16));
    f[2] = bf2f((u16)(v.y & 0xffffu)); f[3] = bf2f((u16)(v.y >> 16));
    f[4] = bf2f((u16)(v.z & 0xffffu)); f[5] = bf2f((u16)(v.z >> 16));
    f[6] = bf2f((u16)(v.w & 0xffffu)); f[7] = bf2f((u16)(v.w >> 16));
}

// ---------- fused fp32->bf16 convert (x/qkv_w/c_proj_w) + rope tables ----------
__global__ __launch_bounds__(256) void prep0(const float* __restrict__ x,
                                             const float* __restrict__ w,
                                             const float* __restrict__ c,
                                             u16* __restrict__ xb,
                                             u16* __restrict__ wb,
                                             u16* __restrict__ cb,
                                             float* __restrict__ ctab,
                                             float* __restrict__ stab) {
    int b = blockIdx.x;
    if (b >= 8192) {   // rope tables: blocks 8192..9215
        int i = (b - 8192) * 256 + threadIdx.x;
        int t = i >> 6, j = i & 63;
        float cc = 1.0f, ss = 0.0f;
        if (j < 32) {
            float f = exp2f(-10.0f * (float)j / 31.0f);
            float th = (float)t * f;
            cc = cosf(th); ss = sinf(th);
        }
        ctab[i] = cc; stab[i] = ss;
        return;
    }
    const float* in;
    u16* out;
    int i;
    if (b < 4096)      { in = x; out = xb; i = b * 256 + threadIdx.x; }
    else if (b < 7168) { in = w; out = wb; i = (b - 4096) * 256 + threadIdx.x; }
    else               { in = c; out = cb; i = (b - 7168) * 256 + threadIdx.x; }
    float4 v = reinterpret_cast<const float4*>(in)[i];
    u16x4 o;
    o.x = f2bf(v.x); o.y = f2bf(v.y); o.z = f2bf(v.z); o.w = f2bf(v.w);
    *reinterpret_cast<u16x4*>(out + 4 * (size_t)i) = o;
}

// ---------- fused QKV GEMM + rmsnorm/rope/v-mix epilogue (BM=64) ----------
__global__ __launch_bounds__(256, 6) void gemm_qkv(const u16* __restrict__ A,
                                                   const u16* __restrict__ B,
                                                   const float* __restrict__ ve,
                                                   const float* __restrict__ lambdas,
                                                   const float* __restrict__ ctab,
                                                   const float* __restrict__ stab,
                                                   u16* __restrict__ Qb,
                                                   u16* __restrict__ Kb,
                                                   u16* __restrict__ Vt) {
    __shared__ u16 smem[12288];   // loop: A[2][2048] @0 | B[2][4096] @4096; epi: [128][72]
    const int K = 1024;
    const int tid = threadIdx.x;
    const int w = tid >> 6, l = tid & 63;
    const int bid = blockIdx.x;
    const int bm = bid & 63, bn = bid >> 6;   // grid 64 x 24
    const int g = l >> 4, c16 = l & 15;
    const int wr = w >> 1, wc = w & 1;        // 2x2 wave quadrants

    f32x4 acc[2][4] = {};                     // [mi][ni]: 32x64 per wave

    auto stage = [&](int bi, int kt) {
        {
            int r = w * 16 + (l >> 2);
            int gs = (l & 3) ^ ((r >> 1) & 3);
            gld_lds(A + (size_t)(bm * 64 + r) * K + kt * 32 + gs * 8,
                    smem + bi * 2048 + w * 512);
        }
#pragma unroll
        for (int cc = 0; cc < 2; ++cc) {
            int c = 2 * w + cc;
            int r = 16 * c + (l >> 2);
            int gs = (l & 3) ^ ((r >> 1) & 3);
            gld_lds(B + (size_t)(bn * 128 + r) * K + kt * 32 + gs * 8,
                    smem + 4096 + bi * 4096 + c * 512);
        }
    };

    const int NT = K >> 5;
    stage(0, 0);
    __syncthreads();
    for (int kt = 0; kt < NT; ++kt) {
        int cur = kt & 1;
        if (kt + 1 < NT) stage(cur ^ 1, kt + 1);
        bf16x8 af[2], bf[4];
#pragma unroll
        for (int mi = 0; mi < 2; ++mi) {
            int r = wr * 32 + mi * 16 + c16;
            int sl = g ^ ((r >> 1) & 3);
            af[mi] = ld_frag(smem + cur * 2048 + r * 32 + sl * 8);
        }
#pragma unroll
        for (int ni = 0; ni < 4; ++ni) {
            int r = wc * 64 + ni * 16 + c16;
            int sl = g ^ ((r >> 1) & 3);
            bf[ni] = ld_frag(smem + 4096 + cur * 4096 + r * 32 + sl * 8);
        }
#pragma unroll
        for (int mi = 0; mi < 2; ++mi)
#pragma unroll
            for (int ni = 0; ni < 4; ++ni)
                acc[mi][ni] = __builtin_amdgcn_mfma_f32_16x16x32_bf16(
                    af[mi], bf[ni], acc[mi][ni], 0, 0, 0);
        __syncthreads();
    }

    const int which = bn >> 3, h = bn & 7;
    if (which < 2) {
#pragma unroll
        for (int mi = 0; mi < 2; ++mi)
#pragma unroll
            for (int ni = 0; ni < 4; ++ni) {
                int col = wc * 64 + ni * 16 + c16;
                int row0 = wr * 32 + mi * 16 + g * 4;
#pragma unroll
                for (int r = 0; r < 4; ++r)
                    smem[(row0 + r) * 136 + col] = f2bf(acc[mi][ni][r]);
            }
        __syncthreads();
        const int row = tid >> 2, p = tid & 3;
        const int t = bm * 64 + row;
        const u16* src = smem + row * 136;
        const int j0 = p * 16;
        float x1[16], x2[16];
#pragma unroll
        for (int e = 0; e < 16; e += 8) {
            unp8(*(const uint4*)(src + j0 + e), x1 + e);
            unp8(*(const uint4*)(src + 64 + j0 + e), x2 + e);
        }
        float ss = 0.0f;
#pragma unroll
        for (int e = 0; e < 16; ++e) ss += x1[e] * x1[e] + x2[e] * x2[e];
        ss += __shfl_xor(ss, 1);
        ss += __shfl_xor(ss, 2);
        float rs = rsqrtf(ss * (1.0f / 128.0f) + 1.1920929e-07f);
        if (which == 0) rs *= 0.12f;        // fold ATTN_SCALE into q
        u16* dst = (which ? Kb : Qb) + ((size_t)h * 4096 + t) * 128;
        u16 o1[16], o2[16];
#pragma unroll
        for (int e = 0; e < 16; ++e) {
            int j = j0 + e;
            float c = ctab[t * 64 + j], s = stab[t * 64 + j];
            float a = x1[e] * rs, b = x2[e] * rs;
            o1[e] = f2bf(a * c + b * s);
            o2[e] = f2bf(b * c - a * s);
        }
#pragma unroll
        for (int e = 0; e < 16; e += 4) {
            *(u16x4*)(dst + j0 + e) = *(u16x4*)(o1 + e);
            *(u16x4*)(dst + 64 + j0 + e) = *(u16x4*)(o2 + e);
        }
    } else {
        const float l0 = lambdas[0], l1 = lambdas[1];
#pragma unroll
        for (int mi = 0; mi < 2; ++mi)
#pragma unroll
            for (int ni = 0; ni < 4; ++ni) {
                int col = wc * 64 + ni * 16 + c16;
                int row0 = wr * 32 + mi * 16 + g * 4;
#pragma unroll
                for (int r = 0; r < 4; ++r) {
                    int row = row0 + r;   // 0..63
                    float vv = l0 * acc[mi][ni][r]
                             + l1 * ve[(size_t)(bm * 64 + row) * 1024 + h * 128 + col];
                    int cp = (row & 51) | ((row & 4) << 1) | ((row & 8) >> 1);  // bits 2<->3
                    smem[col * 72 + cp] = f2bf(vv);
                }
            }
        __syncthreads();
        const int d = tid >> 1, seg = tid & 1;
        const u16* lsrc = smem + d * 72 + seg * 32;
        u16* gdst = Vt + ((size_t)h * 128 + d) * 4096 + bm * 64 + seg * 32;
#pragma unroll
        for (int q2 = 0; q2 < 4; ++q2)
            *(uint4*)(gdst + q2 * 8) = *(const uint4*)(lsrc + q2 * 8);
    }
}

// ---------- causal flash attention (R18 proven): uniform-length double-segment ----------
__global__ __launch_bounds__(256) void attn(const u16* __restrict__ Qb,
                                            const u16* __restrict__ Kb,
                                            const u16* __restrict__ Vt,
                                            u16* __restrict__ Op,
                                            float* __restrict__ ssumP) {
    __shared__ u16 smem[3 * 8192];    // [K0 | K1 | V] 16KB each; epilogue reuses as f32
    const int bid = blockIdx.x;
    const int h = bid & 7;                       // head -> XCD affinity
    const int pid = bid >> 3;                    // 0..63
    const int j = pid >> 1;                      // 0..31
    const int half = pid & 1;
    const int tid = threadIdx.x;
    const int w = tid >> 6, l = tid & 63;
    const int qh = w & 1, kvh = w >> 1;          // wave quadrant
    const int l31 = l & 31, hi = l >> 5;
    const int krow = kvh * 32 + l31;

    for (int seg = 0; seg < 2; ++seg) {
        const int qb = seg ? (63 - j) : j;
        const int part = seg ? (1 - half) : half;
        const int s = (qb + 1) >> 1;
        const int t0 = part ? s : 0;
        const int t1 = part ? (qb + 1) : s;
        const int qg = qb * 64 + qh * 32 + l31;  // this lane's q row (global)

        bf16x8 qf[8];
        {
            const u16* qp = Qb + ((size_t)h * 4096 + qg) * 128;
#pragma unroll
            for (int dk = 0; dk < 8; ++dk) qf[dk] = ld_frag(qp + dk * 16 + hi * 8);
        }

        const u16* kp[4];
        const u16* vp[4];
#pragma unroll
        for (int cc = 0; cc < 4; ++cc) {
            int c = 4 * w + cc;
            int rK = 4 * c + (l >> 4);
            int gsK = (l & 15) ^ (rK & 7);
            kp[cc] = Kb + ((size_t)h * 4096 + t0 * 64 + rK) * 128 + gsK * 8;
            int rV = 8 * c + (l >> 3);
            int gsV = (l & 7) ^ (rV & 7);
            vp[cc] = Vt + ((size_t)h * 128 + rV) * 4096 + t0 * 64 + gsV * 8;
        }

        f32x16 o[4] = {};   // O^T: lane holds d = dt*32+(r&3)+8*(r>>2)+4*hi, q=l31
        float ssum = 0.0f;

        if (t0 < t1) {
#pragma unroll
            for (int cc = 0; cc < 4; ++cc) {
                gld_lds(kp[cc], smem + (4 * w + cc) * 512);
                kp[cc] += 8192;           // 64 rows * 128
            }
            __syncthreads();

            int cur = 0;
            for (int t = t0; t < t1; ++t) {
                if (t + 1 < t1) {
#pragma unroll
                    for (int cc = 0; cc < 4; ++cc) {
                        gld_lds(kp[cc], smem + (cur ^ 1) * 8192 + (4 * w + cc) * 512);
                        kp[cc] += 8192;
                    }
                }
#pragma unroll
                for (int cc = 0; cc < 4; ++cc) {
                    gld_lds(vp[cc], smem + 16384 + (4 * w + cc) * 512);
                    vp[cc] += 64;
                }

                const u16* sKc = smem + cur * 8192;
                f32x16 st = {};
                __builtin_amdgcn_s_setprio(1);
#pragma unroll
                for (int dk = 0; dk < 8; ++dk) {
                    int sl = (2 * dk + hi) ^ (krow & 7);
                    bf16x8 kf = ld_frag(sKc + krow * 128 + sl * 8);
                    st = __builtin_amdgcn_mfma_f32_32x32x16_bf16(kf, qf[dk], st, 0, 0, 0);
                }
                __builtin_amdgcn_s_setprio(0);

                float pv[16];
                if (t == qb) {
#pragma unroll
                    for (int r = 0; r < 16; ++r) {
                        int kvg = t * 64 + kvh * 32 + (r & 3) + 8 * (r >> 2) + 4 * hi;
                        pv[r] = (kvg <= qg) ? __expf(st[r]) : 0.0f;
                    }
                } else {
#pragma unroll
                    for (int r = 0; r < 16; ++r) pv[r] = __expf(st[r]);
                }
                float ps = 0.0f;
#pragma unroll
                for (int i = 0; i < 16; ++i) ps += pv[i];
                ssum += ps;

                bf16x8 pb[2];
#pragma unroll
                for (int m = 0; m < 2; ++m) {
                    uint4 u;
                    u.x = pk_bf16(pv[8 * m + 0], pv[8 * m + 1]);
                    u.y = pk_bf16(pv[8 * m + 2], pv[8 * m + 3]);
                    u.z = pk_bf16(pv[8 * m + 4], pv[8 * m + 5]);
                    u.w = pk_bf16(pv[8 * m + 6], pv[8 * m + 7]);
                    pb[m] = __builtin_bit_cast(bf16x8, u);
                }

                __syncthreads();   // V(t) landed (also drains K(t+1) prefetch)

                const u16* sVc = smem + 16384;
                __builtin_amdgcn_s_setprio(1);
#pragma unroll
                for (int m = 0; m < 2; ++m) {
#pragma unroll
                    for (int dt = 0; dt < 4; ++dt) {
                        int drow = dt * 32 + l31;
                        int sl = (4 * kvh + 2 * m + hi) ^ (drow & 7);
                        bf16x8 vf = ld_frag(sVc + drow * 64 + sl * 8);
                        o[dt] = __builtin_amdgcn_mfma_f32_32x32x16_bf16(vf, pb[m], o[dt], 0, 0, 0);
                    }
                }
                __builtin_amdgcn_s_setprio(0);
                __syncthreads();   // all waves done with V-buf; K[cur^1] ready
                cur ^= 1;
            }
        } else {
            __syncthreads();   // keep block converged for epilogue smem use
        }

        // ---- segment epilogue: merge kv-halves (fp32 in LDS), store bf16 partial ----
        ssum += __shfl_xor(ssum, 32);

        float* sO = (float*)smem;               // [2 qh][32 q][132 d-pad] f32
        float* sS = (float*)smem + 8448;        // [2 qh][32 q] f32
        if (kvh == 1) {
            float* base = sO + (qh * 32 + l31) * 132;
#pragma unroll
            for (int dt = 0; dt < 4; ++dt)
#pragma unroll
                for (int i = 0; i < 4; ++i) {
                    int d0 = dt * 32 + i * 8 + hi * 4;
                    float4 v = {o[dt][4 * i + 0], o[dt][4 * i + 1],
                                o[dt][4 * i + 2], o[dt][4 * i + 3]};
                    *(float4*)(base + d0) = v;
                }
            if (hi == 0) sS[qh * 32 + l31] = ssum;
        }
        __syncthreads();
        if (kvh == 0) {
            float stot = ssum + sS[qh * 32 + l31];
            const float* base = sO + (qh * 32 + l31) * 132;
            u16* orow = Op + (size_t)part * OPHALF + ((size_t)(h * 4096 + qg)) * 128;
#pragma unroll
            for (int dt = 0; dt < 4; ++dt)
#pragma unroll
                for (int i = 0; i < 4; ++i) {
                    int d0 = dt * 32 + i * 8 + hi * 4;
                    float4 prev = *(const float4*)(base + d0);
                    u16x4 ov;
                    ov.x = f2bf(o[dt][4 * i + 0] + prev.x);
                    ov.y = f2bf(o[dt][4 * i + 1] + prev.y);
                    ov.z = f2bf(o[dt][4 * i + 2] + prev.z);
                    ov.w = f2bf(o[dt][4 * i + 3] + prev.w);
                    *(u16x4*)(orow + d0) = ov;
                }
            if (hi == 0) ssumP[part * 32768 + h * 4096 + qg] = stot;
        }
        __syncthreads();   // epilogue smem reads done before next segment stages
    }
}

// ---------- out-proj GEMM with fused partial-combine on A path ----------
// A[r][k] = (Op0[h][r][d] + Op1[h][r][d]) / (s0+s1),  h=k>>7, d=k&127.
// A staged via regs (T14 issue-early/write-late); B via global_load_lds.
// 64x64 tile, grid 64x16 = 1024 blocks (4 blocks/CU).
__global__ __launch_bounds__(256) void gemm_out(const u16* __restrict__ Op,
                                                const float* __restrict__ ssumP,
                                                const u16* __restrict__ B,
                                                float* __restrict__ Cout) {
    __shared__ u16 smem[8192];   // A[2][2048] @0 | B[2][2048] @4096
    const int K = 1024;
    const int tid = threadIdx.x;
    const int w = tid >> 6, l = tid & 63;
    const int bm = blockIdx.x & 63, bn = blockIdx.x >> 6;   // grid 64 x 16
    const int g = l >> 4, c16 = l & 15;
    const int wr = w >> 1, wc = w & 1;
    const int rr = w * 16 + (l >> 2);        // A row in tile
    const int R  = bm * 64 + rr;             // global row
    const int gsA = (l & 3) ^ ((rr >> 1) & 3);

    f32x4 acc[2][2] = {};

    auto ldA = [&](int kt, uint4& a, uint4& b2, float& inv) {
        int h = kt >> 2;
        int d0 = (kt & 3) * 32 + gsA * 8;
        const u16* p0 = Op + ((size_t)(h * 4096 + R)) * 128 + d0;
        a  = *(const uint4*)p0;
        b2 = *(const uint4*)(p0 + OPHALF);
        inv = 1.0f / (ssumP[h * 4096 + R] + ssumP[32768 + h * 4096 + R]);
    };
    auto wrA = [&](int bi, uint4 a, uint4 b2, float inv) {
        const u16* pa = (const u16*)&a;
        const u16* pb = (const u16*)&b2;
        u32 pk[4];
#pragma unroll
        for (int i = 0; i < 4; ++i) {
            float lo = (bf2f(pa[2 * i])     + bf2f(pb[2 * i]))     * inv;
            float hi = (bf2f(pa[2 * i + 1]) + bf2f(pb[2 * i + 1])) * inv;
            pk[i] = pk_bf16(lo, hi);
        }
        *(uint4*)(smem + bi * 2048 + rr * 32 + (l & 3) * 8) = *(uint4*)pk;
    };
    auto stageB = [&](int bi, int kt) {
        int r = w * 16 + (l >> 2);
        int gs = (l & 3) ^ ((r >> 1) & 3);
        gld_lds(B + (size_t)(bn * 64 + r) * K + kt * 32 + gs * 8,
                smem + 4096 + bi * 2048 + w * 512);
    };

    const int NT = K >> 5;
    {
        uint4 a0, b0; float inv0;
        ldA(0, a0, b0, inv0);
        stageB(0, 0);
        wrA(0, a0, b0, inv0);
    }
    __syncthreads();
    for (int kt = 0; kt < NT; ++kt) {
        int cur = kt & 1;
        uint4 aN, bN; float invN;
        const bool pre = (kt + 1 < NT);
        if (pre) {
            ldA(kt + 1, aN, bN, invN);     // issue early (hides under MFMA)
            stageB(cur ^ 1, kt + 1);
        }
        bf16x8 af[2], bf[2];
#pragma unroll
        for (int mi = 0; mi < 2; ++mi) {
            int r = wr * 32 + mi * 16 + c16;
            int sl = g ^ ((r >> 1) & 3);
            af[mi] = ld_frag(smem + cur * 2048 + r * 32 + sl * 8);
        }
#pragma unroll
        for (int ni = 0; ni < 2; ++ni) {
            int r = wc * 32 + ni * 16 + c16;
            int sl = g ^ ((r >> 1) & 3);
            bf[ni] = ld_frag(smem + 4096 + cur * 2048 + r * 32 + sl * 8);
        }
#pragma unroll
        for (int mi = 0; mi < 2; ++mi)
#pragma unroll
            for (int ni = 0; ni < 2; ++ni)
                acc[mi][ni] = __builtin_amdgcn_mfma_f32_16x16x32_bf16(
                    af[mi], bf[ni], acc[mi][ni], 0, 0, 0);
        if (pre) wrA(cur ^ 1, aN, bN, invN);   // write late (into other buffer)
        __syncthreads();
    }
#pragma unroll
    for (int mi = 0; mi < 2; ++mi) {
#pragma unroll
        for (int ni = 0; ni < 2; ++ni) {
            int col = bn * 64 + wc * 32 + ni * 16 + c16;
            int row0 = bm * 64 + wr * 32 + mi * 16 + g * 4;
#pragma unroll
            for (int r = 0; r < 4; ++r)
                Cout[(size_t)(row0 + r) * 1024 + col] = acc[mi][ni][r];
        }
    }
}

// ---------- launch ----------
extern "C" void kernel_launch(void* const* d_in, const int* in_sizes, int n_in,
                              void* d_out, int out_size, void* d_ws, size_t ws_size,
                              hipStream_t stream) {
    const float* x = (const float*)d_in[0];
    const float* ve = (const float*)d_in[1];
    const float* qkv_w = (const float*)d_in[2];
    const float* lambdas = (const float*)d_in[3];
    const float* c_proj_w = (const float*)d_in[4];

    char* ws = (char*)d_ws;
    size_t o = 0;
    u16* qkvb = (u16*)(ws + o); o += (size_t)4096 * 3072 * 2;   // pure scratch
    u16* xb   = (u16*)(ws + o); o += (size_t)4096 * 1024 * 2;   // dead after gemm_qkv
    u16* wb   = (u16*)(ws + o); o += (size_t)3072 * 1024 * 2;   // dead after gemm_qkv
    u16* cb   = (u16*)(ws + o); o += (size_t)1024 * 1024 * 2;
    u16* Qb   = (u16*)(ws + o); o += (size_t)8 * 4096 * 128 * 2;
    u16* Kb   = (u16*)(ws + o); o += (size_t)8 * 4096 * 128 * 2;
    u16* Vt   = (u16*)(ws + o); o += (size_t)8 * 4096 * 128 * 2;
    u16* Yb   = (u16*)(ws + o); o += (size_t)4096 * 1024 * 2;   // unused now
    float* ctab = (float*)(ws + o); o += (size_t)4096 * 64 * 4;
    float* stab = (float*)(ws + o); o += (size_t)4096 * 64 * 4;
    (void)Yb;
    // partial O (2 x 8MB bf16 = 16MB) reuses qkvb; partial ssum reuses wb.
    u16* Op      = qkvb;
    float* ssumP = (float*)wb;

    prep0<<<9216, 256, 0, stream>>>(x, qkv_w, c_proj_w, xb, wb, cb, ctab, stab);
    gemm_qkv<<<64 * 24, 256, 0, stream>>>(xb, wb, ve, lambdas, ctab, stab, Qb, Kb, Vt);
    attn<<<512, 256, 0, stream>>>(Qb, Kb, Vt, Op, ssumP);
    gemm_out<<<64 * 16, 256, 0, stream>>>(Op, ssumP, cb, (float*)d_out);
}

// Round 24
// 138.036 us; speedup vs baseline: 1.0359x; 1.0359x over previous
//
#include <hip/hip_runtime.h>
#include <hip/hip_bf16.h>

typedef __attribute__((ext_vector_type(4))) float f32x4;
typedef __attribute__((ext_vector_type(16))) float f32x16;
typedef __attribute__((ext_vector_type(8))) __bf16 bf16x8;
typedef unsigned short u16;
typedef unsigned int u32;
typedef __attribute__((ext_vector_type(4))) u16 u16x4;

// ---------- helpers ----------
__device__ __forceinline__ u16 f2bf(float f) {
    u32 u = __builtin_bit_cast(u32, f);
    u32 r = (u + 0x7FFFu + ((u >> 16) & 1u)) >> 16;
    return (u16)r;
}
__device__ __forceinline__ float bf2f(u16 h) {
    return __builtin_bit_cast(float, ((u32)h) << 16);
}
__device__ __forceinline__ bf16x8 ld_frag(const u16* p) {
    uint4 v = *reinterpret_cast<const uint4*>(p);
    return __builtin_bit_cast(bf16x8, v);
}
__device__ __forceinline__ void gld_lds(const u16* gp, u16* lp) {
    __builtin_amdgcn_global_load_lds(
        (const __attribute__((address_space(1))) u32*)gp,
        (__attribute__((address_space(3))) u32*)lp, 16, 0, 0);
}
__device__ __forceinline__ u32 pk_bf16(float lo, float hi) {
    u32 r;
    asm("v_cvt_pk_bf16_f32 %0, %1, %2" : "=v"(r) : "v"(lo), "v"(hi));
    return r;
}
__device__ __forceinline__ void unp8(uint4 v, float* f) {
    f[0] = bf2f((u16)(v.x & 0xffffu)); f[1] = bf2f((u16)(v.x >> 16));
    f[2] = bf2f((u16)(v.y & 0xffffu)); f[3] = bf2f((u16)(v.y >> 16));
    f[4] = bf2f((u16)(v.z & 0xffffu)); f[5] = bf2f((u16)(v.z >> 16));
    f[6] = bf2f((u16)(v.w & 0xffffu)); f[7] = bf2f((u16)(v.w >> 16));
}

// ---------- fused fp32 -> bf16 convert for x / qkv_w / c_proj_w ----------
__global__ __launch_bounds__(256) void cvt3(const float* __restrict__ x,
                                            const float* __restrict__ w,
                                            const float* __restrict__ c,
                                            u16* __restrict__ xb,
                                            u16* __restrict__ wb,
                                            u16* __restrict__ cb) {
    int b = blockIdx.x;
    const float* in;
    u16* out;
    int i;
    if (b < 4096)      { in = x; out = xb; i = b * 256 + threadIdx.x; }
    else if (b < 7168) { in = w; out = wb; i = (b - 4096) * 256 + threadIdx.x; }
    else               { in = c; out = cb; i = (b - 7168) * 256 + threadIdx.x; }
    float4 v = reinterpret_cast<const float4*>(in)[i];
    u16x4 o;
    o.x = f2bf(v.x); o.y = f2bf(v.y); o.z = f2bf(v.z); o.w = f2bf(v.w);
    *reinterpret_cast<u16x4*>(out + 4 * (size_t)i) = o;
}

// ---------- rope tables: ctab/stab [T=4096][64] fp32 ----------
__global__ __launch_bounds__(256) void rope_tab(float* __restrict__ ctab,
                                                float* __restrict__ stab) {
    int i = blockIdx.x * 256 + threadIdx.x;
    int t = i >> 6, j = i & 63;
    float c = 1.0f, s = 0.0f;
    if (j < 32) {
        float f = exp2f(-10.0f * (float)j / 31.0f);
        float th = (float)t * f;
        c = cosf(th); s = sinf(th);
    }
    ctab[i] = c; stab[i] = s;
}

// ---------- fused QKV GEMM + rmsnorm/rope/v-mix epilogue (BM=64) ----------
__global__ __launch_bounds__(256, 6) void gemm_qkv(const u16* __restrict__ A,
                                                   const u16* __restrict__ B,
                                                   const float* __restrict__ ve,
                                                   const float* __restrict__ lambdas,
                                                   const float* __restrict__ ctab,
                                                   const float* __restrict__ stab,
                                                   u16* __restrict__ Qb,
                                                   u16* __restrict__ Kb,
                                                   u16* __restrict__ Vt) {
    __shared__ u16 smem[12288];   // loop: A[2][2048] @0 | B[2][4096] @4096; epi: [128][72]
    const int K = 1024;
    const int tid = threadIdx.x;
    const int w = tid >> 6, l = tid & 63;
    const int bid = blockIdx.x;
    const int bm = bid & 63, bn = bid >> 6;   // grid 64 x 24
    const int g = l >> 4, c16 = l & 15;
    const int wr = w >> 1, wc = w & 1;        // 2x2 wave quadrants

    f32x4 acc[2][4] = {};                     // [mi][ni]: 32x64 per wave

    auto stage = [&](int bi, int kt) {
        {
            int r = w * 16 + (l >> 2);
            int gs = (l & 3) ^ ((r >> 1) & 3);
            gld_lds(A + (size_t)(bm * 64 + r) * K + kt * 32 + gs * 8,
                    smem + bi * 2048 + w * 512);
        }
#pragma unroll
        for (int cc = 0; cc < 2; ++cc) {
            int c = 2 * w + cc;
            int r = 16 * c + (l >> 2);
            int gs = (l & 3) ^ ((r >> 1) & 3);
            gld_lds(B + (size_t)(bn * 128 + r) * K + kt * 32 + gs * 8,
                    smem + 4096 + bi * 4096 + c * 512);
        }
    };

    const int NT = K >> 5;
    stage(0, 0);
    __syncthreads();
    for (int kt = 0; kt < NT; ++kt) {
        int cur = kt & 1;
        if (kt + 1 < NT) stage(cur ^ 1, kt + 1);
        bf16x8 af[2], bf[4];
#pragma unroll
        for (int mi = 0; mi < 2; ++mi) {
            int r = wr * 32 + mi * 16 + c16;
            int sl = g ^ ((r >> 1) & 3);
            af[mi] = ld_frag(smem + cur * 2048 + r * 32 + sl * 8);
        }
#pragma unroll
        for (int ni = 0; ni < 4; ++ni) {
            int r = wc * 64 + ni * 16 + c16;
            int sl = g ^ ((r >> 1) & 3);
            bf[ni] = ld_frag(smem + 4096 + cur * 4096 + r * 32 + sl * 8);
        }
#pragma unroll
        for (int mi = 0; mi < 2; ++mi)
#pragma unroll
            for (int ni = 0; ni < 4; ++ni)
                acc[mi][ni] = __builtin_amdgcn_mfma_f32_16x16x32_bf16(
                    af[mi], bf[ni], acc[mi][ni], 0, 0, 0);
        __syncthreads();
    }

    const int which = bn >> 3, h = bn & 7;
    if (which < 2) {
#pragma unroll
        for (int mi = 0; mi < 2; ++mi)
#pragma unroll
            for (int ni = 0; ni < 4; ++ni) {
                int col = wc * 64 + ni * 16 + c16;
                int row0 = wr * 32 + mi * 16 + g * 4;
#pragma unroll
                for (int r = 0; r < 4; ++r)
                    smem[(row0 + r) * 136 + col] = f2bf(acc[mi][ni][r]);
            }
        __syncthreads();
        const int row = tid >> 2, p = tid & 3;
        const int t = bm * 64 + row;
        const u16* src = smem + row * 136;
        const int j0 = p * 16;
        float x1[16], x2[16];
#pragma unroll
        for (int e = 0; e < 16; e += 8) {
            unp8(*(const uint4*)(src + j0 + e), x1 + e);
            unp8(*(const uint4*)(src + 64 + j0 + e), x2 + e);
        }
        float ss = 0.0f;
#pragma unroll
        for (int e = 0; e < 16; ++e) ss += x1[e] * x1[e] + x2[e] * x2[e];
        ss += __shfl_xor(ss, 1);
        ss += __shfl_xor(ss, 2);
        float rs = rsqrtf(ss * (1.0f / 128.0f) + 1.1920929e-07f);
        if (which == 0) rs *= 0.12f;        // fold ATTN_SCALE into q
        u16* dst = (which ? Kb : Qb) + ((size_t)h * 4096 + t) * 128;
        u16 o1[16], o2[16];
#pragma unroll
        for (int e = 0; e < 16; ++e) {
            int j = j0 + e;
            float c = ctab[t * 64 + j], s = stab[t * 64 + j];
            float a = x1[e] * rs, b = x2[e] * rs;
            o1[e] = f2bf(a * c + b * s);
            o2[e] = f2bf(b * c - a * s);
        }
#pragma unroll
        for (int e = 0; e < 16; e += 4) {
            *(u16x4*)(dst + j0 + e) = *(u16x4*)(o1 + e);
            *(u16x4*)(dst + 64 + j0 + e) = *(u16x4*)(o2 + e);
        }
    } else {
        const float l0 = lambdas[0], l1 = lambdas[1];
#pragma unroll
        for (int mi = 0; mi < 2; ++mi)
#pragma unroll
            for (int ni = 0; ni < 4; ++ni) {
                int col = wc * 64 + ni * 16 + c16;
                int row0 = wr * 32 + mi * 16 + g * 4;
#pragma unroll
                for (int r = 0; r < 4; ++r) {
                    int row = row0 + r;   // 0..63
                    float vv = l0 * acc[mi][ni][r]
                             + l1 * ve[(size_t)(bm * 64 + row) * 1024 + h * 128 + col];
                    int cp = (row & 51) | ((row & 4) << 1) | ((row & 8) >> 1);  // bits 2<->3
                    smem[col * 72 + cp] = f2bf(vv);
                }
            }
        __syncthreads();
        const int d = tid >> 1, seg = tid & 1;
        const u16* lsrc = smem + d * 72 + seg * 32;
        u16* gdst = Vt + ((size_t)h * 128 + d) * 4096 + bm * 64 + seg * 32;
#pragma unroll
        for (int q2 = 0; q2 < 4; ++q2)
            *(uint4*)(gdst + q2 * 8) = *(const uint4*)(lsrc + q2 * 8);
    }
}

// ---------- NT GEMM (out-proj): 64x64 tile for TLP (4 blocks/CU) ----------
__global__ __launch_bounds__(256) void gemm_nt_f32(const u16* __restrict__ A,
                                                   const u16* __restrict__ B,
                                                   float* __restrict__ Cout,
                                                   int M, int N, int K, int ldc) {
    __shared__ u16 smem[8192];   // A[2][2048] @0 | B[2][2048] @4096
    const int tid = threadIdx.x;
    const int w = tid >> 6, l = tid & 63;
    const int bm = blockIdx.x & 63, bn = blockIdx.x >> 6;   // grid 64 x 16
    const int g = l >> 4, c16 = l & 15;
    const int wr = w >> 1, wc = w & 1;

    f32x4 acc[2][2] = {};

    auto stage = [&](int bi, int kt) {
        {
            int r = w * 16 + (l >> 2);
            int gs = (l & 3) ^ ((r >> 1) & 3);
            gld_lds(A + (size_t)(bm * 64 + r) * K + kt * 32 + gs * 8,
                    smem + bi * 2048 + w * 512);
        }
        {
            int r = w * 16 + (l >> 2);
            int gs = (l & 3) ^ ((r >> 1) & 3);
            gld_lds(B + (size_t)(bn * 64 + r) * K + kt * 32 + gs * 8,
                    smem + 4096 + bi * 2048 + w * 512);
        }
    };

    const int NT = K >> 5;
    stage(0, 0);
    __syncthreads();
    for (int kt = 0; kt < NT; ++kt) {
        int cur = kt & 1;
        if (kt + 1 < NT) stage(cur ^ 1, kt + 1);
        bf16x8 af[2], bf[2];
#pragma unroll
        for (int mi = 0; mi < 2; ++mi) {
            int r = wr * 32 + mi * 16 + c16;
            int sl = g ^ ((r >> 1) & 3);
            af[mi] = ld_frag(smem + cur * 2048 + r * 32 + sl * 8);
        }
#pragma unroll
        for (int ni = 0; ni < 2; ++ni) {
            int r = wc * 32 + ni * 16 + c16;
            int sl = g ^ ((r >> 1) & 3);
            bf[ni] = ld_frag(smem + 4096 + cur * 2048 + r * 32 + sl * 8);
        }
#pragma unroll
        for (int mi = 0; mi < 2; ++mi)
#pragma unroll
            for (int ni = 0; ni < 2; ++ni)
                acc[mi][ni] = __builtin_amdgcn_mfma_f32_16x16x32_bf16(
                    af[mi], bf[ni], acc[mi][ni], 0, 0, 0);
        __syncthreads();
    }
#pragma unroll
    for (int mi = 0; mi < 2; ++mi) {
#pragma unroll
        for (int ni = 0; ni < 2; ++ni) {
            int col = bn * 64 + wc * 32 + ni * 16 + c16;
            int row0 = bm * 64 + wr * 32 + mi * 16 + g * 4;
#pragma unroll
            for (int r = 0; r < 4; ++r)
                Cout[(size_t)(row0 + r) * ldc + col] = acc[mi][ni][r];
        }
    }
}

// ---------- causal flash attention (R18 proven): uniform-length double-segment ----------
// Partial O stored bf16 (halves HBM write + combine read); in-block merge stays fp32.
#define OPHALF 4194304  /* 8*4096*128 elems per part */
__global__ __launch_bounds__(256) void attn(const u16* __restrict__ Qb,
                                            const u16* __restrict__ Kb,
                                            const u16* __restrict__ Vt,
                                            u16* __restrict__ Op,
                                            float* __restrict__ ssumP) {
    __shared__ u16 smem[3 * 8192];    // [K0 | K1 | V] 16KB each; epilogue reuses as f32
    const int bid = blockIdx.x;
    const int h = bid & 7;                       // head -> XCD affinity
    const int pid = bid >> 3;                    // 0..63
    const int j = pid >> 1;                      // 0..31
    const int half = pid & 1;
    const int tid = threadIdx.x;
    const int w = tid >> 6, l = tid & 63;
    const int qh = w & 1, kvh = w >> 1;          // wave quadrant
    const int l31 = l & 31, hi = l >> 5;
    const int krow = kvh * 32 + l31;

    for (int seg = 0; seg < 2; ++seg) {
        const int qb = seg ? (63 - j) : j;
        const int part = seg ? (1 - half) : half;
        const int s = (qb + 1) >> 1;
        const int t0 = part ? s : 0;
        const int t1 = part ? (qb + 1) : s;
        const int qg = qb * 64 + qh * 32 + l31;  // this lane's q row (global)

        bf16x8 qf[8];
        {
            const u16* qp = Qb + ((size_t)h * 4096 + qg) * 128;
#pragma unroll
            for (int dk = 0; dk < 8; ++dk) qf[dk] = ld_frag(qp + dk * 16 + hi * 8);
        }

        const u16* kp[4];
        const u16* vp[4];
#pragma unroll
        for (int cc = 0; cc < 4; ++cc) {
            int c = 4 * w + cc;
            int rK = 4 * c + (l >> 4);
            int gsK = (l & 15) ^ (rK & 7);
            kp[cc] = Kb + ((size_t)h * 4096 + t0 * 64 + rK) * 128 + gsK * 8;
            int rV = 8 * c + (l >> 3);
            int gsV = (l & 7) ^ (rV & 7);
            vp[cc] = Vt + ((size_t)h * 128 + rV) * 4096 + t0 * 64 + gsV * 8;
        }

        f32x16 o[4] = {};   // O^T: lane holds d = dt*32+(r&3)+8*(r>>2)+4*hi, q=l31
        float ssum = 0.0f;

        if (t0 < t1) {
#pragma unroll
            for (int cc = 0; cc < 4; ++cc) {
                gld_lds(kp[cc], smem + (4 * w + cc) * 512);
                kp[cc] += 8192;           // 64 rows * 128
            }
            __syncthreads();

            int cur = 0;
            for (int t = t0; t < t1; ++t) {
                if (t + 1 < t1) {
#pragma unroll
                    for (int cc = 0; cc < 4; ++cc) {
                        gld_lds(kp[cc], smem + (cur ^ 1) * 8192 + (4 * w + cc) * 512);
                        kp[cc] += 8192;
                    }
                }
#pragma unroll
                for (int cc = 0; cc < 4; ++cc) {
                    gld_lds(vp[cc], smem + 16384 + (4 * w + cc) * 512);
                    vp[cc] += 64;
                }

                const u16* sKc = smem + cur * 8192;
                f32x16 st = {};
                __builtin_amdgcn_s_setprio(1);
#pragma unroll
                for (int dk = 0; dk < 8; ++dk) {
                    int sl = (2 * dk + hi) ^ (krow & 7);
                    bf16x8 kf = ld_frag(sKc + krow * 128 + sl * 8);
                    st = __builtin_amdgcn_mfma_f32_32x32x16_bf16(kf, qf[dk], st, 0, 0, 0);
                }
                __builtin_amdgcn_s_setprio(0);

                float pv[16];
                if (t == qb) {
#pragma unroll
                    for (int r = 0; r < 16; ++r) {
                        int kvg = t * 64 + kvh * 32 + (r & 3) + 8 * (r >> 2) + 4 * hi;
                        pv[r] = (kvg <= qg) ? __expf(st[r]) : 0.0f;
                    }
                } else {
#pragma unroll
                    for (int r = 0; r < 16; ++r) pv[r] = __expf(st[r]);
                }
                float ps = 0.0f;
#pragma unroll
                for (int i = 0; i < 16; ++i) ps += pv[i];
                ssum += ps;

                bf16x8 pb[2];
#pragma unroll
                for (int m = 0; m < 2; ++m) {
                    uint4 u;
                    u.x = pk_bf16(pv[8 * m + 0], pv[8 * m + 1]);
                    u.y = pk_bf16(pv[8 * m + 2], pv[8 * m + 3]);
                    u.z = pk_bf16(pv[8 * m + 4], pv[8 * m + 5]);
                    u.w = pk_bf16(pv[8 * m + 6], pv[8 * m + 7]);
                    pb[m] = __builtin_bit_cast(bf16x8, u);
                }

                __syncthreads();   // V(t) landed (also drains K(t+1) prefetch)

                const u16* sVc = smem + 16384;
                __builtin_amdgcn_s_setprio(1);
#pragma unroll
                for (int m = 0; m < 2; ++m) {
#pragma unroll
                    for (int dt = 0; dt < 4; ++dt) {
                        int drow = dt * 32 + l31;
                        int sl = (4 * kvh + 2 * m + hi) ^ (drow & 7);
                        bf16x8 vf = ld_frag(sVc + drow * 64 + sl * 8);
                        o[dt] = __builtin_amdgcn_mfma_f32_32x32x16_bf16(vf, pb[m], o[dt], 0, 0, 0);
                    }
                }
                __builtin_amdgcn_s_setprio(0);
                __syncthreads();   // all waves done with V-buf; K[cur^1] ready
                cur ^= 1;
            }
        } else {
            __syncthreads();   // keep block converged for epilogue smem use
        }

        // ---- segment epilogue: merge kv-halves (fp32 in LDS), store bf16 partial ----
        ssum += __shfl_xor(ssum, 32);

        float* sO = (float*)smem;               // [2 qh][32 q][132 d-pad] f32
        float* sS = (float*)smem + 8448;        // [2 qh][32 q] f32
        if (kvh == 1) {
            float* base = sO + (qh * 32 + l31) * 132;
#pragma unroll
            for (int dt = 0; dt < 4; ++dt)
#pragma unroll
                for (int i = 0; i < 4; ++i) {
                    int d0 = dt * 32 + i * 8 + hi * 4;
                    float4 v = {o[dt][4 * i + 0], o[dt][4 * i + 1],
                                o[dt][4 * i + 2], o[dt][4 * i + 3]};
                    *(float4*)(base + d0) = v;
                }
            if (hi == 0) sS[qh * 32 + l31] = ssum;
        }
        __syncthreads();
        if (kvh == 0) {
            float stot = ssum + sS[qh * 32 + l31];
            const float* base = sO + (qh * 32 + l31) * 132;
            u16* orow = Op + (size_t)part * OPHALF + ((size_t)(h * 4096 + qg)) * 128;
#pragma unroll
            for (int dt = 0; dt < 4; ++dt)
#pragma unroll
                for (int i = 0; i < 4; ++i) {
                    int d0 = dt * 32 + i * 8 + hi * 4;
                    float4 prev = *(const float4*)(base + d0);
                    u16x4 ov;
                    ov.x = f2bf(o[dt][4 * i + 0] + prev.x);
                    ov.y = f2bf(o[dt][4 * i + 1] + prev.y);
                    ov.z = f2bf(o[dt][4 * i + 2] + prev.z);
                    ov.w = f2bf(o[dt][4 * i + 3] + prev.w);
                    *(u16x4*)(orow + d0) = ov;
                }
            if (hi == 0) ssumP[part * 32768 + h * 4096 + qg] = stot;
        }
        __syncthreads();   // epilogue smem reads done before next segment stages
    }
}

// ---------- combine parts: y = (O0+O1)/(s0+s1) -> Y bf16 [T][1024] ----------
__global__ __launch_bounds__(256) void combine(const u16* __restrict__ Op,
                                               const float* __restrict__ ssumP,
                                               u16* __restrict__ Y) {
    int i = blockIdx.x * 256 + threadIdx.x;   // over [8][4096][32] quads of 4 d
    int d4 = i & 31;
    int hq = i >> 5;
    int h = hq >> 12, q = hq & 4095;
    u16x4 a = ((const u16x4*)Op)[i];
    u16x4 b = ((const u16x4*)(Op + OPHALF))[i];
    float inv = 1.0f / (ssumP[hq] + ssumP[32768 + hq]);
    u16x4 ov;
    ov.x = f2bf((bf2f(a.x) + bf2f(b.x)) * inv);
    ov.y = f2bf((bf2f(a.y) + bf2f(b.y)) * inv);
    ov.z = f2bf((bf2f(a.z) + bf2f(b.z)) * inv);
    ov.w = f2bf((bf2f(a.w) + bf2f(b.w)) * inv);
    *(u16x4*)(Y + (size_t)q * 1024 + h * 128 + d4 * 4) = ov;
}

// ---------- launch ----------
extern "C" void kernel_launch(void* const* d_in, const int* in_sizes, int n_in,
                              void* d_out, int out_size, void* d_ws, size_t ws_size,
                              hipStream_t stream) {
    const float* x = (const float*)d_in[0];
    const float* ve = (const float*)d_in[1];
    const float* qkv_w = (const float*)d_in[2];
    const float* lambdas = (const float*)d_in[3];
    const float* c_proj_w = (const float*)d_in[4];

    char* ws = (char*)d_ws;
    size_t o = 0;
    u16* qkvb = (u16*)(ws + o); o += (size_t)4096 * 3072 * 2;   // pure scratch
    u16* xb   = (u16*)(ws + o); o += (size_t)4096 * 1024 * 2;   // dead after gemm_qkv
    u16* wb   = (u16*)(ws + o); o += (size_t)3072 * 1024 * 2;   // dead after gemm_qkv
    u16* cb   = (u16*)(ws + o); o += (size_t)1024 * 1024 * 2;
    u16* Qb   = (u16*)(ws + o); o += (size_t)8 * 4096 * 128 * 2;
    u16* Kb   = (u16*)(ws + o); o += (size_t)8 * 4096 * 128 * 2;
    u16* Vt   = (u16*)(ws + o); o += (size_t)8 * 4096 * 128 * 2;
    u16* Yb   = (u16*)(ws + o); o += (size_t)4096 * 1024 * 2;
    float* ctab = (float*)(ws + o); o += (size_t)4096 * 64 * 4;
    float* stab = (float*)(ws + o); o += (size_t)4096 * 64 * 4;
    // partial O (2 x 8MB bf16 = 16MB) reuses qkvb; partial ssum reuses wb.
    u16* Op      = qkvb;
    float* ssumP = (float*)wb;

    cvt3<<<8192, 256, 0, stream>>>(x, qkv_w, c_proj_w, xb, wb, cb);
    rope_tab<<<1024, 256, 0, stream>>>(ctab, stab);
    gemm_qkv<<<64 * 24, 256, 0, stream>>>(xb, wb, ve, lambdas, ctab, stab, Qb, Kb, Vt);
    attn<<<512, 256, 0, stream>>>(Qb, Kb, Vt, Op, ssumP);
    combine<<<4096, 256, 0, stream>>>(Op, ssumP, Yb);
    gemm_nt_f32<<<64 * 16, 256, 0, stream>>>(Yb, cb, (float*)d_out, 4096, 1024, 1024, 1024);
}

// Round 25
// 135.632 us; speedup vs baseline: 1.0542x; 1.0177x over previous
//
#include <hip/hip_runtime.h>
#include <hip/hip_bf16.h>

typedef __attribute__((ext_vector_type(4))) float f32x4;
typedef __attribute__((ext_vector_type(16))) float f32x16;
typedef __attribute__((ext_vector_type(8))) __bf16 bf16x8;
typedef unsigned short u16;
typedef unsigned int u32;
typedef __attribute__((ext_vector_type(4))) u16 u16x4;

#define OPHALF 4194304  /* 8*4096*128 elems per part */

// ---------- helpers ----------
__device__ __forceinline__ u16 f2bf(float f) {
    u32 u = __builtin_bit_cast(u32, f);
    u32 r = (u + 0x7FFFu + ((u >> 16) & 1u)) >> 16;
    return (u16)r;
}
__device__ __forceinline__ float bf2f(u16 h) {
    return __builtin_bit_cast(float, ((u32)h) << 16);
}
__device__ __forceinline__ bf16x8 ld_frag(const u16* p) {
    uint4 v = *reinterpret_cast<const uint4*>(p);
    return __builtin_bit_cast(bf16x8, v);
}
__device__ __forceinline__ void gld_lds(const u16* gp, u16* lp) {
    __builtin_amdgcn_global_load_lds(
        (const __attribute__((address_space(1))) u32*)gp,
        (__attribute__((address_space(3))) u32*)lp, 16, 0, 0);
}
__device__ __forceinline__ u32 pk_bf16(float lo, float hi) {
    u32 r;
    asm("v_cvt_pk_bf16_f32 %0, %1, %2" : "=v"(r) : "v"(lo), "v"(hi));
    return r;
}
__device__ __forceinline__ void unp8(uint4 v, float* f) {
    f[0] = bf2f((u16)(v.x & 0xffffu)); f[1] = bf2f((u16)(v.x >> 16));
    f[2] = bf2f((u16)(v.y & 0xffffu)); f[3] = bf2f((u16)(v.y >> 16));
    f[4] = bf2f((u16)(v.z & 0xffffu)); f[5] = bf2f((u16)(v.z >> 16));
    f[6] = bf2f((u16)(v.w & 0xffffu)); f[7] = bf2f((u16)(v.w >> 16));
}

// ---------- fused fp32->bf16 convert (x/qkv_w/c_proj_w) + rope tables ----------
__global__ __launch_bounds__(256) void prep0(const float* __restrict__ x,
                                             const float* __restrict__ w,
                                             const float* __restrict__ c,
                                             u16* __restrict__ xb,
                                             u16* __restrict__ wb,
                                             u16* __restrict__ cb,
                                             float* __restrict__ ctab,
                                             float* __restrict__ stab) {
    int b = blockIdx.x;
    if (b >= 8192) {   // rope tables: blocks 8192..9215
        int i = (b - 8192) * 256 + threadIdx.x;
        int t = i >> 6, j = i & 63;
        float cc = 1.0f, ss = 0.0f;
        if (j < 32) {
            float f = exp2f(-10.0f * (float)j / 31.0f);
            float th = (float)t * f;
            cc = cosf(th); ss = sinf(th);
        }
        ctab[i] = cc; stab[i] = ss;
        return;
    }
    const float* in;
    u16* out;
    int i;
    if (b < 4096)      { in = x; out = xb; i = b * 256 + threadIdx.x; }
    else if (b < 7168) { in = w; out = wb; i = (b - 4096) * 256 + threadIdx.x; }
    else               { in = c; out = cb; i = (b - 7168) * 256 + threadIdx.x; }
    float4 v = reinterpret_cast<const float4*>(in)[i];
    u16x4 o;
    o.x = f2bf(v.x); o.y = f2bf(v.y); o.z = f2bf(v.z); o.w = f2bf(v.w);
    *reinterpret_cast<u16x4*>(out + 4 * (size_t)i) = o;
}

// ---------- fused QKV GEMM + rmsnorm/rope/v-mix epilogue (BM=64) ----------
__global__ __launch_bounds__(256, 6) void gemm_qkv(const u16* __restrict__ A,
                                                   const u16* __restrict__ B,
                                                   const float* __restrict__ ve,
                                                   const float* __restrict__ lambdas,
                                                   const float* __restrict__ ctab,
                                                   const float* __restrict__ stab,
                                                   u16* __restrict__ Qb,
                                                   u16* __restrict__ Kb,
                                                   u16* __restrict__ Vt) {
    __shared__ u16 smem[12288];   // loop: A[2][2048] @0 | B[2][4096] @4096; epi: [128][72]
    const int K = 1024;
    const int tid = threadIdx.x;
    const int w = tid >> 6, l = tid & 63;
    const int bid = blockIdx.x;
    const int bm = bid & 63, bn = bid >> 6;   // grid 64 x 24
    const int g = l >> 4, c16 = l & 15;
    const int wr = w >> 1, wc = w & 1;        // 2x2 wave quadrants

    f32x4 acc[2][4] = {};                     // [mi][ni]: 32x64 per wave

    auto stage = [&](int bi, int kt) {
        {
            int r = w * 16 + (l >> 2);
            int gs = (l & 3) ^ ((r >> 1) & 3);
            gld_lds(A + (size_t)(bm * 64 + r) * K + kt * 32 + gs * 8,
                    smem + bi * 2048 + w * 512);
        }
#pragma unroll
        for (int cc = 0; cc < 2; ++cc) {
            int c = 2 * w + cc;
            int r = 16 * c + (l >> 2);
            int gs = (l & 3) ^ ((r >> 1) & 3);
            gld_lds(B + (size_t)(bn * 128 + r) * K + kt * 32 + gs * 8,
                    smem + 4096 + bi * 4096 + c * 512);
        }
    };

    const int NT = K >> 5;
    stage(0, 0);
    __syncthreads();
    for (int kt = 0; kt < NT; ++kt) {
        int cur = kt & 1;
        if (kt + 1 < NT) stage(cur ^ 1, kt + 1);
        bf16x8 af[2], bf[4];
#pragma unroll
        for (int mi = 0; mi < 2; ++mi) {
            int r = wr * 32 + mi * 16 + c16;
            int sl = g ^ ((r >> 1) & 3);
            af[mi] = ld_frag(smem + cur * 2048 + r * 32 + sl * 8);
        }
#pragma unroll
        for (int ni = 0; ni < 4; ++ni) {
            int r = wc * 64 + ni * 16 + c16;
            int sl = g ^ ((r >> 1) & 3);
            bf[ni] = ld_frag(smem + 4096 + cur * 4096 + r * 32 + sl * 8);
        }
#pragma unroll
        for (int mi = 0; mi < 2; ++mi)
#pragma unroll
            for (int ni = 0; ni < 4; ++ni)
                acc[mi][ni] = __builtin_amdgcn_mfma_f32_16x16x32_bf16(
                    af[mi], bf[ni], acc[mi][ni], 0, 0, 0);
        __syncthreads();
    }

    const int which = bn >> 3, h = bn & 7;
    if (which < 2) {
#pragma unroll
        for (int mi = 0; mi < 2; ++mi)
#pragma unroll
            for (int ni = 0; ni < 4; ++ni) {
                int col = wc * 64 + ni * 16 + c16;
                int row0 = wr * 32 + mi * 16 + g * 4;
#pragma unroll
                for (int r = 0; r < 4; ++r)
                    smem[(row0 + r) * 136 + col] = f2bf(acc[mi][ni][r]);
            }
        __syncthreads();
        const int row = tid >> 2, p = tid & 3;
        const int t = bm * 64 + row;
        const u16* src = smem + row * 136;
        const int j0 = p * 16;
        float x1[16], x2[16];
#pragma unroll
        for (int e = 0; e < 16; e += 8) {
            unp8(*(const uint4*)(src + j0 + e), x1 + e);
            unp8(*(const uint4*)(src + 64 + j0 + e), x2 + e);
        }
        float ss = 0.0f;
#pragma unroll
        for (int e = 0; e < 16; ++e) ss += x1[e] * x1[e] + x2[e] * x2[e];
        ss += __shfl_xor(ss, 1);
        ss += __shfl_xor(ss, 2);
        float rs = rsqrtf(ss * (1.0f / 128.0f) + 1.1920929e-07f);
        if (which == 0) rs *= 0.12f;        // fold ATTN_SCALE into q
        u16* dst = (which ? Kb : Qb) + ((size_t)h * 4096 + t) * 128;
        u16 o1[16], o2[16];
#pragma unroll
        for (int e = 0; e < 16; ++e) {
            int j = j0 + e;
            float c = ctab[t * 64 + j], s = stab[t * 64 + j];
            float a = x1[e] * rs, b = x2[e] * rs;
            o1[e] = f2bf(a * c + b * s);
            o2[e] = f2bf(b * c - a * s);
        }
#pragma unroll
        for (int e = 0; e < 16; e += 4) {
            *(u16x4*)(dst + j0 + e) = *(u16x4*)(o1 + e);
            *(u16x4*)(dst + 64 + j0 + e) = *(u16x4*)(o2 + e);
        }
    } else {
        const float l0 = lambdas[0], l1 = lambdas[1];
#pragma unroll
        for (int mi = 0; mi < 2; ++mi)
#pragma unroll
            for (int ni = 0; ni < 4; ++ni) {
                int col = wc * 64 + ni * 16 + c16;
                int row0 = wr * 32 + mi * 16 + g * 4;
#pragma unroll
                for (int r = 0; r < 4; ++r) {
                    int row = row0 + r;   // 0..63
                    float vv = l0 * acc[mi][ni][r]
                             + l1 * ve[(size_t)(bm * 64 + row) * 1024 + h * 128 + col];
                    int cp = (row & 51) | ((row & 4) << 1) | ((row & 8) >> 1);  // bits 2<->3
                    smem[col * 72 + cp] = f2bf(vv);
                }
            }
        __syncthreads();
        const int d = tid >> 1, seg = tid & 1;
        const u16* lsrc = smem + d * 72 + seg * 32;
        u16* gdst = Vt + ((size_t)h * 128 + d) * 4096 + bm * 64 + seg * 32;
#pragma unroll
        for (int q2 = 0; q2 < 4; ++q2)
            *(uint4*)(gdst + q2 * 8) = *(const uint4*)(lsrc + q2 * 8);
    }
}

// ---------- NT GEMM (out-proj): 64x64 tile for TLP (4 blocks/CU) ----------
__global__ __launch_bounds__(256) void gemm_nt_f32(const u16* __restrict__ A,
                                                   const u16* __restrict__ B,
                                                   float* __restrict__ Cout,
                                                   int M, int N, int K, int ldc) {
    __shared__ u16 smem[8192];   // A[2][2048] @0 | B[2][2048] @4096
    const int tid = threadIdx.x;
    const int w = tid >> 6, l = tid & 63;
    const int bm = blockIdx.x & 63, bn = blockIdx.x >> 6;   // grid 64 x 16
    const int g = l >> 4, c16 = l & 15;
    const int wr = w >> 1, wc = w & 1;

    f32x4 acc[2][2] = {};

    auto stage = [&](int bi, int kt) {
        {
            int r = w * 16 + (l >> 2);
            int gs = (l & 3) ^ ((r >> 1) & 3);
            gld_lds(A + (size_t)(bm * 64 + r) * K + kt * 32 + gs * 8,
                    smem + bi * 2048 + w * 512);
        }
        {
            int r = w * 16 + (l >> 2);
            int gs = (l & 3) ^ ((r >> 1) & 3);
            gld_lds(B + (size_t)(bn * 64 + r) * K + kt * 32 + gs * 8,
                    smem + 4096 + bi * 2048 + w * 512);
        }
    };

    const int NT = K >> 5;
    stage(0, 0);
    __syncthreads();
    for (int kt = 0; kt < NT; ++kt) {
        int cur = kt & 1;
        if (kt + 1 < NT) stage(cur ^ 1, kt + 1);
        bf16x8 af[2], bf[2];
#pragma unroll
        for (int mi = 0; mi < 2; ++mi) {
            int r = wr * 32 + mi * 16 + c16;
            int sl = g ^ ((r >> 1) & 3);
            af[mi] = ld_frag(smem + cur * 2048 + r * 32 + sl * 8);
        }
#pragma unroll
        for (int ni = 0; ni < 2; ++ni) {
            int r = wc * 32 + ni * 16 + c16;
            int sl = g ^ ((r >> 1) & 3);
            bf[ni] = ld_frag(smem + 4096 + cur * 2048 + r * 32 + sl * 8);
        }
#pragma unroll
        for (int mi = 0; mi < 2; ++mi)
#pragma unroll
            for (int ni = 0; ni < 2; ++ni)
                acc[mi][ni] = __builtin_amdgcn_mfma_f32_16x16x32_bf16(
                    af[mi], bf[ni], acc[mi][ni], 0, 0, 0);
        __syncthreads();
    }
#pragma unroll
    for (int mi = 0; mi < 2; ++mi) {
#pragma unroll
        for (int ni = 0; ni < 2; ++ni) {
            int col = bn * 64 + wc * 32 + ni * 16 + c16;
            int row0 = bm * 64 + wr * 32 + mi * 16 + g * 4;
#pragma unroll
            for (int r = 0; r < 4; ++r)
                Cout[(size_t)(row0 + r) * ldc + col] = acc[mi][ni][r];
        }
    }
}

// ---------- causal flash attention (R18 proven): uniform-length double-segment ----------
__global__ __launch_bounds__(256) void attn(const u16* __restrict__ Qb,
                                            const u16* __restrict__ Kb,
                                            const u16* __restrict__ Vt,
                                            u16* __restrict__ Op,
                                            float* __restrict__ ssumP) {
    __shared__ u16 smem[3 * 8192];    // [K0 | K1 | V] 16KB each; epilogue reuses as f32
    const int bid = blockIdx.x;
    const int h = bid & 7;                       // head -> XCD affinity
    const int pid = bid >> 3;                    // 0..63
    const int j = pid >> 1;                      // 0..31
    const int half = pid & 1;
    const int tid = threadIdx.x;
    const int w = tid >> 6, l = tid & 63;
    const int qh = w & 1, kvh = w >> 1;          // wave quadrant
    const int l31 = l & 31, hi = l >> 5;
    const int krow = kvh * 32 + l31;

    for (int seg = 0; seg < 2; ++seg) {
        const int qb = seg ? (63 - j) : j;
        const int part = seg ? (1 - half) : half;
        const int s = (qb + 1) >> 1;
        const int t0 = part ? s : 0;
        const int t1 = part ? (qb + 1) : s;
        const int qg = qb * 64 + qh * 32 + l31;  // this lane's q row (global)

        bf16x8 qf[8];
        {
            const u16* qp = Qb + ((size_t)h * 4096 + qg) * 128;
#pragma unroll
            for (int dk = 0; dk < 8; ++dk) qf[dk] = ld_frag(qp + dk * 16 + hi * 8);
        }

        const u16* kp[4];
        const u16* vp[4];
#pragma unroll
        for (int cc = 0; cc < 4; ++cc) {
            int c = 4 * w + cc;
            int rK = 4 * c + (l >> 4);
            int gsK = (l & 15) ^ (rK & 7);
            kp[cc] = Kb + ((size_t)h * 4096 + t0 * 64 + rK) * 128 + gsK * 8;
            int rV = 8 * c + (l >> 3);
            int gsV = (l & 7) ^ (rV & 7);
            vp[cc] = Vt + ((size_t)h * 128 + rV) * 4096 + t0 * 64 + gsV * 8;
        }

        f32x16 o[4] = {};   // O^T: lane holds d = dt*32+(r&3)+8*(r>>2)+4*hi, q=l31
        float ssum = 0.0f;

        if (t0 < t1) {
#pragma unroll
            for (int cc = 0; cc < 4; ++cc) {
                gld_lds(kp[cc], smem + (4 * w + cc) * 512);
                kp[cc] += 8192;           // 64 rows * 128
            }
            __syncthreads();

            int cur = 0;
            for (int t = t0; t < t1; ++t) {
                if (t + 1 < t1) {
#pragma unroll
                    for (int cc = 0; cc < 4; ++cc) {
                        gld_lds(kp[cc], smem + (cur ^ 1) * 8192 + (4 * w + cc) * 512);
                        kp[cc] += 8192;
                    }
                }
#pragma unroll
                for (int cc = 0; cc < 4; ++cc) {
                    gld_lds(vp[cc], smem + 16384 + (4 * w + cc) * 512);
                    vp[cc] += 64;
                }

                const u16* sKc = smem + cur * 8192;
                f32x16 st = {};
                __builtin_amdgcn_s_setprio(1);
#pragma unroll
                for (int dk = 0; dk < 8; ++dk) {
                    int sl = (2 * dk + hi) ^ (krow & 7);
                    bf16x8 kf = ld_frag(sKc + krow * 128 + sl * 8);
                    st = __builtin_amdgcn_mfma_f32_32x32x16_bf16(kf, qf[dk], st, 0, 0, 0);
                }
                __builtin_amdgcn_s_setprio(0);

                float pv[16];
                if (t == qb) {
#pragma unroll
                    for (int r = 0; r < 16; ++r) {
                        int kvg = t * 64 + kvh * 32 + (r & 3) + 8 * (r >> 2) + 4 * hi;
                        pv[r] = (kvg <= qg) ? __expf(st[r]) : 0.0f;
                    }
                } else {
#pragma unroll
                    for (int r = 0; r < 16; ++r) pv[r] = __expf(st[r]);
                }
                float ps = 0.0f;
#pragma unroll
                for (int i = 0; i < 16; ++i) ps += pv[i];
                ssum += ps;

                bf16x8 pb[2];
#pragma unroll
                for (int m = 0; m < 2; ++m) {
                    uint4 u;
                    u.x = pk_bf16(pv[8 * m + 0], pv[8 * m + 1]);
                    u.y = pk_bf16(pv[8 * m + 2], pv[8 * m + 3]);
                    u.z = pk_bf16(pv[8 * m + 4], pv[8 * m + 5]);
                    u.w = pk_bf16(pv[8 * m + 6], pv[8 * m + 7]);
                    pb[m] = __builtin_bit_cast(bf16x8, u);
                }

                __syncthreads();   // V(t) landed (also drains K(t+1) prefetch)

                const u16* sVc = smem + 16384;
                __builtin_amdgcn_s_setprio(1);
#pragma unroll
                for (int m = 0; m < 2; ++m) {
#pragma unroll
                    for (int dt = 0; dt < 4; ++dt) {
                        int drow = dt * 32 + l31;
                        int sl = (4 * kvh + 2 * m + hi) ^ (drow & 7);
                        bf16x8 vf = ld_frag(sVc + drow * 64 + sl * 8);
                        o[dt] = __builtin_amdgcn_mfma_f32_32x32x16_bf16(vf, pb[m], o[dt], 0, 0, 0);
                    }
                }
                __builtin_amdgcn_s_setprio(0);
                __syncthreads();   // all waves done with V-buf; K[cur^1] ready
                cur ^= 1;
            }
        } else {
            __syncthreads();   // keep block converged for epilogue smem use
        }

        // ---- segment epilogue: merge kv-halves (fp32 in LDS), store bf16 partial ----
        ssum += __shfl_xor(ssum, 32);

        float* sO = (float*)smem;               // [2 qh][32 q][132 d-pad] f32
        float* sS = (float*)smem + 8448;        // [2 qh][32 q] f32
        if (kvh == 1) {
            float* base = sO + (qh * 32 + l31) * 132;
#pragma unroll
            for (int dt = 0; dt < 4; ++dt)
#pragma unroll
                for (int i = 0; i < 4; ++i) {
                    int d0 = dt * 32 + i * 8 + hi * 4;
                    float4 v = {o[dt][4 * i + 0], o[dt][4 * i + 1],
                                o[dt][4 * i + 2], o[dt][4 * i + 3]};
                    *(float4*)(base + d0) = v;
                }
            if (hi == 0) sS[qh * 32 + l31] = ssum;
        }
        __syncthreads();
        if (kvh == 0) {
            float stot = ssum + sS[qh * 32 + l31];
            const float* base = sO + (qh * 32 + l31) * 132;
            u16* orow = Op + (size_t)part * OPHALF + ((size_t)(h * 4096 + qg)) * 128;
#pragma unroll
            for (int dt = 0; dt < 4; ++dt)
#pragma unroll
                for (int i = 0; i < 4; ++i) {
                    int d0 = dt * 32 + i * 8 + hi * 4;
                    float4 prev = *(const float4*)(base + d0);
                    u16x4 ov;
                    ov.x = f2bf(o[dt][4 * i + 0] + prev.x);
                    ov.y = f2bf(o[dt][4 * i + 1] + prev.y);
                    ov.z = f2bf(o[dt][4 * i + 2] + prev.z);
                    ov.w = f2bf(o[dt][4 * i + 3] + prev.w);
                    *(u16x4*)(orow + d0) = ov;
                }
            if (hi == 0) ssumP[part * 32768 + h * 4096 + qg] = stot;
        }
        __syncthreads();   // epilogue smem reads done before next segment stages
    }
}

// ---------- combine parts: y = (O0+O1)/(s0+s1) -> Y bf16 [T][1024] ----------
__global__ __launch_bounds__(256) void combine(const u16* __restrict__ Op,
                                               const float* __restrict__ ssumP,
                                               u16* __restrict__ Y) {
    int i = blockIdx.x * 256 + threadIdx.x;   // over [8][4096][32] quads of 4 d
    int d4 = i & 31;
    int hq = i >> 5;
    int h = hq >> 12, q = hq & 4095;
    u16x4 a = ((const u16x4*)Op)[i];
    u16x4 b = ((const u16x4*)(Op + OPHALF))[i];
    float inv = 1.0f / (ssumP[hq] + ssumP[32768 + hq]);
    u16x4 ov;
    ov.x = f2bf((bf2f(a.x) + bf2f(b.x)) * inv);
    ov.y = f2bf((bf2f(a.y) + bf2f(b.y)) * inv);
    ov.z = f2bf((bf2f(a.z) + bf2f(b.z)) * inv);
    ov.w = f2bf((bf2f(a.w) + bf2f(b.w)) * inv);
    *(u16x4*)(Y + (size_t)q * 1024 + h * 128 + d4 * 4) = ov;
}

// ---------- launch ----------
extern "C" void kernel_launch(void* const* d_in, const int* in_sizes, int n_in,
                              void* d_out, int out_size, void* d_ws, size_t ws_size,
                              hipStream_t stream) {
    const float* x = (const float*)d_in[0];
    const float* ve = (const float*)d_in[1];
    const float* qkv_w = (const float*)d_in[2];
    const float* lambdas = (const float*)d_in[3];
    const float* c_proj_w = (const float*)d_in[4];

    char* ws = (char*)d_ws;
    size_t o = 0;
    u16* qkvb = (u16*)(ws + o); o += (size_t)4096 * 3072 * 2;   // pure scratch
    u16* xb   = (u16*)(ws + o); o += (size_t)4096 * 1024 * 2;   // dead after gemm_qkv
    u16* wb   = (u16*)(ws + o); o += (size_t)3072 * 1024 * 2;   // dead after gemm_qkv
    u16* cb   = (u16*)(ws + o); o += (size_t)1024 * 1024 * 2;
    u16* Qb   = (u16*)(ws + o); o += (size_t)8 * 4096 * 128 * 2;
    u16* Kb   = (u16*)(ws + o); o += (size_t)8 * 4096 * 128 * 2;
    u16* Vt   = (u16*)(ws + o); o += (size_t)8 * 4096 * 128 * 2;
    u16* Yb   = (u16*)(ws + o); o += (size_t)4096 * 1024 * 2;
    float* ctab = (float*)(ws + o); o += (size_t)4096 * 64 * 4;
    float* stab = (float*)(ws + o); o += (size_t)4096 * 64 * 4;
    // partial O (2 x 8MB bf16 = 16MB) reuses qkvb; partial ssum reuses wb.
    u16* Op      = qkvb;
    float* ssumP = (float*)wb;

    prep0<<<9216, 256, 0, stream>>>(x, qkv_w, c_proj_w, xb, wb, cb, ctab, stab);
    gemm_qkv<<<64 * 24, 256, 0, stream>>>(xb, wb, ve, lambdas, ctab, stab, Qb, Kb, Vt);
    attn<<<512, 256, 0, stream>>>(Qb, Kb, Vt, Op, ssumP);
    combine<<<4096, 256, 0, stream>>>(Op, ssumP, Yb);
    gemm_nt_f32<<<64 * 16, 256, 0, stream>>>(Yb, cb, (float*)d_out, 4096, 1024, 1024, 1024);
}